// Round 9
// baseline (86.813 us; speedup 1.0000x reference)
//
#include <hip/hip_runtime.h>

#define D 64
#define K 1024
#define NVEC 65536
#define MB 128            // vectors per block
#define NBLK (NVEC / MB)  // 512
#define WAVES 8           // 512 threads
#define KPW (K / WAVES)   // 128 codes per wave
#define TILES (KPW / 16)  // 8
#define NG (MB / 16)      // 8 vector groups per wave

typedef __attribute__((ext_vector_type(8))) short bf16x8;
typedef __attribute__((ext_vector_type(4))) float f32x4;
typedef __attribute__((ext_vector_type(4))) int i32x4;

// single v_perm_b32: {hi16(b), hi16(a)} == bf16x2(trunc(a), trunc(b))
__device__ inline unsigned pk2t(float a, float b) {
    return __builtin_amdgcn_perm(__builtin_bit_cast(unsigned, b),
                                 __builtin_bit_cast(unsigned, a), 0x07060302u);
}

// ---------------------------------------------------------------------------
// Prep: codebook f32 -> bf16 (trunc) + biased neg half-norms 1 - 0.5||e||^2.
// One-time 256 KB read; keeps the per-block codebook work out of the main loop.
// ---------------------------------------------------------------------------
__global__ __launch_bounds__(256) void vq_prep(const float* __restrict__ emb,
                                               unsigned* __restrict__ ebf_u,
                                               float* __restrict__ hb) {
    const int k = blockIdx.x * 256 + threadIdx.x;   // 0..1023
    const float4* e4 = reinterpret_cast<const float4*>(emb + (size_t)k * D);
    unsigned* o = ebf_u + (size_t)k * (D / 2);
    float s = 0.f;
#pragma unroll
    for (int i = 0; i < D / 4; ++i) {
        const float4 v = e4[i];
        s = fmaf(v.x, v.x, s); s = fmaf(v.y, v.y, s);
        s = fmaf(v.z, v.z, s); s = fmaf(v.w, v.w, s);
        o[i * 2]     = pk2t(v.x, v.y);
        o[i * 2 + 1] = pk2t(v.z, v.w);
    }
    hb[k] = 1.0f - 0.5f * s;
}

// ---------------------------------------------------------------------------
// Main: 512 thr (8 waves), 128 vectors/block, wave w owns codes [w*128,+128).
// MFMA score GEMM, packed argmax (score bits | index, v_max_i32), loss via
// winning-score unpack. 16 waves/CU at grid 512.
// ---------------------------------------------------------------------------
__global__ __launch_bounds__(512, 4) void vq_main(const float* __restrict__ z,
                                                  const float* __restrict__ emb,
                                                  const unsigned short* __restrict__ ebf,
                                                  const float* __restrict__ hb,
                                                  float* __restrict__ out,
                                                  float* __restrict__ pP) {
    __shared__ __align__(16) char zl[MB * 128];   // 16 KB bf16 z-tile [v][d], XOR-swizzled
    __shared__ int   wv[WAVES * MB];              // 4 KB
    __shared__ int   fin[MB];
    __shared__ float red[512];                    // 2 KB

    const int tid = threadIdx.x;
    const int blk = blockIdx.x;
    const int b   = blk >> 3;              // batch (8 blocks per batch)
    const int hw0 = (blk & 7) * MB;        // first spatial pos
    const float* zb = z + (size_t)b * (D * 1024) + hw0;

    const int wave = tid >> 6;
    const int lane = tid & 63;
    const int cw   = wave * KPW;

    // ---- Phase A: stage z tile f32 [d][v] -> LDS bf16 [v][d] swizzled; sum(z^2)
    float zacc = 0.f;
    {
        const int v4 = tid & 31;           // 4-vector group (128 v)
        const int d4 = tid >> 5;           // 4-dim group (64 d)
        float4 r[4];
#pragma unroll
        for (int i = 0; i < 4; ++i)
            r[i] = *reinterpret_cast<const float4*>(zb + (size_t)(d4 * 4 + i) * 1024 + v4 * 4);
        const float* rf = reinterpret_cast<const float*>(r);
#pragma unroll
        for (int n = 0; n < 16; ++n) zacc = fmaf(rf[n], rf[n], zacc);
#pragma unroll
        for (int j = 0; j < 4; ++j) {
            const int v = v4 * 4 + j;
            uint2 pk;
            pk.x = pk2t(rf[0 * 4 + j], rf[1 * 4 + j]);
            pk.y = pk2t(rf[2 * 4 + j], rf[3 * 4 + j]);
            const int byte = v * 128 + ((d4 * 8) ^ ((v & 7) << 4));
            *reinterpret_cast<uint2*>(zl + byte) = pk;
        }
    }
    __syncthreads();

    const int l16 = lane & 15;
    const int lg  = lane >> 4;    // 0..3

    // ---- B-frags: this block's 128 vectors in registers
    bf16x8 bfr[NG][2];
#pragma unroll
    for (int g = 0; g < NG; ++g)
#pragma unroll
        for (int h = 0; h < 2; ++h) {
            const int v = g * 16 + l16;
            const int byte = v * 128 + (((h * 64) + lg * 16) ^ ((v & 7) << 4));
            bfr[g][h] = *reinterpret_cast<const bf16x8*>(zl + byte);
        }

    // ---- k-loop: 8 tiles fully unrolled; packed argmax
    int best[NG];
#pragma unroll
    for (int g = 0; g < NG; ++g) best[g] = 0;
#pragma unroll
    for (int kt = 0; kt < TILES; ++kt) {
        const int cbase = cw + kt * 16;
        const bf16x8 a0 = *reinterpret_cast<const bf16x8*>(ebf + (size_t)(cbase + l16) * 64 + lg * 8);
        const bf16x8 a1 = *reinterpret_cast<const bf16x8*>(ebf + (size_t)(cbase + l16) * 64 + 32 + lg * 8);
        const f32x4 ci = *reinterpret_cast<const f32x4*>(hb + cbase + lg * 4);  // 1 - 0.5||e||^2
        const int idx0 = cbase + lg * 4;
#pragma unroll
        for (int g = 0; g < NG; ++g) {
            f32x4 c = ci;
            c = __builtin_amdgcn_mfma_f32_16x16x32_bf16(a0, bfr[g][0], c, 0, 0, 0);
            c = __builtin_amdgcn_mfma_f32_16x16x32_bf16(a1, bfr[g][1], c, 0, 0, 0);
#pragma unroll
            for (int r = 0; r < 4; ++r) {
                const int pk = (int)((__builtin_bit_cast(unsigned, c[r]) & 0xFFFFFC00u)
                                     | (unsigned)(idx0 + r));
                best[g] = best[g] > pk ? best[g] : pk;
            }
        }
    }

    // ---- cross-lane argmax (over lg groups)
#pragma unroll
    for (int g = 0; g < NG; ++g) {
        int tv = best[g];
        int o = __shfl_xor(tv, 16, 64); tv = tv > o ? tv : o;
        o = __shfl_xor(tv, 32, 64);     tv = tv > o ? tv : o;
        if (lane < 16) wv[wave * MB + g * 16 + l16] = tv;
    }
    __syncthreads();

    // ---- cross-wave combine; unpack winning score for the loss
    float tcon = 0.f;
    if (tid < MB) {
        int tv = wv[tid];
#pragma unroll
        for (int w = 1; w < WAVES; ++w) {
            const int o = wv[w * MB + tid];
            tv = tv > o ? tv : o;
        }
        fin[tid] = tv & (K - 1);
        tcon = __builtin_bit_cast(float, (unsigned)tv & 0xFFFFFC00u) - 1.0f;  // z.e - 0.5||e||^2
    }
    __syncthreads();

    // ---- output: gather exact f32 code rows, write out[b][d][hw] coalesced
    {
        const int v  = tid & 127;
        const int dh = tid >> 7;              // 0..3, 16 dims each
        const int idx = fin[v];
        const float4* eq4 = reinterpret_cast<const float4*>(emb + (size_t)idx * D + dh * 16);
        float* ob = out + (size_t)b * (D * 1024) + hw0 + v;
#pragma unroll
        for (int i = 0; i < 4; ++i) {
            const float4 q = eq4[i];
            const int d = dh * 16 + i * 4;
            ob[(size_t)(d + 0) * 1024] = q.x;
            ob[(size_t)(d + 1) * 1024] = q.y;
            ob[(size_t)(d + 2) * 1024] = q.z;
            ob[(size_t)(d + 3) * 1024] = q.w;
        }
    }

    // ---- block partial: sum(z^2) - 2*sum(t), fixed-order tree
    red[tid] = zacc - 2.f * tcon;
    __syncthreads();
#pragma unroll
    for (int s = 256; s > 0; s >>= 1) {
        if (tid < s) red[tid] += red[tid + s];
        __syncthreads();
    }
    if (tid == 0) pP[blk] = red[0];
}

// ---------------------------------------------------------------------------
// Loss epilogue: 1 block; kernel boundary guarantees pP visibility.
// ---------------------------------------------------------------------------
__global__ __launch_bounds__(256) void vq_loss(const float* __restrict__ pP,
                                               float* __restrict__ loss_out) {
    __shared__ float red[256];
    float s = 0.f;
    for (int i = threadIdx.x; i < NBLK; i += 256) s += pP[i];
    red[threadIdx.x] = s;
    __syncthreads();
#pragma unroll
    for (int st = 128; st > 0; st >>= 1) {
        if (threadIdx.x < st) red[threadIdx.x] += red[threadIdx.x + st];
        __syncthreads();
    }
    if (threadIdx.x == 0)
        loss_out[0] = 1.25f * red[0] * (1.0f / (float)((size_t)NVEC * D));
}

extern "C" void kernel_launch(void* const* d_in, const int* in_sizes, int n_in,
                              void* d_out, int out_size, void* d_ws, size_t ws_size,
                              hipStream_t stream) {
    const float* z   = (const float*)d_in[0];   // [64, 64, 32, 32]
    const float* emb = (const float*)d_in[1];   // [1024, 64]
    float* out = (float*)d_out;                 // 4194304 quantized + 1 loss

    char* ws = (char*)d_ws;
    unsigned* ebf_u = (unsigned*)ws;            // 128 KB bf16 codebook
    float* hb = (float*)(ws + 131072);          // 4 KB biased neg half-norms
    float* pP = (float*)(ws + 135168);          // 2 KB block partials

    vq_prep<<<K / 256, 256, 0, stream>>>(emb, ebf_u, hb);
    vq_main<<<NBLK, 512, 0, stream>>>(z, emb, (const unsigned short*)ebf_u, hb, out, pP);
    vq_loss<<<1, 256, 0, stream>>>(pP, out + (size_t)NVEC * D);
}

// Round 10
// 35.161 us; speedup vs baseline: 2.4690x; 2.4690x over previous
//
#include <hip/hip_runtime.h>

#define D 64
#define K 1024
#define NVEC 65536
#define MB 64             // vectors per block
#define NBLK (NVEC / MB)  // 1024
#define WAVES 4
#define KPW (K / WAVES)   // 256 codes per wave
#define TILES (KPW / 16)  // 16
#define NG (MB / 16)      // 4 vector groups per wave

typedef __attribute__((ext_vector_type(8))) short bf16x8;
typedef __attribute__((ext_vector_type(4))) float f32x4;

// single v_perm_b32: {hi16(b), hi16(a)} == bf16x2(trunc(a), trunc(b))
__device__ inline unsigned pk2t(float a, float b) {
    return __builtin_amdgcn_perm(__builtin_bit_cast(unsigned, b),
                                 __builtin_bit_cast(unsigned, a), 0x07060302u);
}
__device__ inline int max3i(int a, int b, int c) {   // -> v_max3_i32
    const int m = a > b ? a : b;
    return m > c ? m : c;
}

// ---------------------------------------------------------------------------
// Prep: 128 blocks x 256 thr, 32 threads per codebook row.
// ebf_u[r*32+j] = bf16x2(emb[r][2j], emb[r][2j+1]); hb[r] = 1 - 0.5*||e_r||^2.
// ---------------------------------------------------------------------------
__global__ __launch_bounds__(256) void vq_prep(const float* __restrict__ emb,
                                               unsigned* __restrict__ ebf_u,
                                               float* __restrict__ hb) {
    const int r = blockIdx.x * 8 + (threadIdx.x >> 5);   // 0..1023
    const int j = threadIdx.x & 31;                      // f32-pair within row
    const float2 v = *reinterpret_cast<const float2*>(emb + (size_t)r * D + j * 2);
    ebf_u[(size_t)r * 32 + j] = pk2t(v.x, v.y);
    float s = fmaf(v.x, v.x, v.y * v.y);
#pragma unroll
    for (int off = 1; off < 32; off <<= 1) s += __shfl_xor(s, off, 64);
    if (j == 0) hb[r] = 1.0f - 0.5f * s;
}

// ---------------------------------------------------------------------------
// Main: 256 thr (4 waves), 64 vectors/block, 1024 blocks (4/CU, 16 waves/CU).
// MFMA score GEMM with register-prefetched codebook tiles; packed argmax
// (score bits | index, v_max3_i32); loss via winning-score unpack.
// ---------------------------------------------------------------------------
__global__ __launch_bounds__(256, 4) void vq_main(const float* __restrict__ z,
                                                  const float* __restrict__ emb,
                                                  const unsigned short* __restrict__ ebf,
                                                  const float* __restrict__ hb,
                                                  float* __restrict__ out,
                                                  float* __restrict__ pP) {
    __shared__ __align__(16) char zl[MB * 128];   // 8 KB bf16 z-tile [v][d], XOR-swizzled
    __shared__ int   wv[WAVES * MB];
    __shared__ int   fin[MB];
    __shared__ float red[256];

    const int tid = threadIdx.x;
    const int blk = blockIdx.x;
    const int b   = blk >> 4;              // batch (16 blocks per batch)
    const int hw0 = (blk & 15) * MB;       // first spatial pos
    const float* zb = z + (size_t)b * (D * 1024) + hw0;

    const int wave = tid >> 6;
    const int lane = tid & 63;
    const int cw   = wave * KPW;

    // ---- stage z tile: f32 [d][v] -> LDS bf16 [v][d] swizzled; f32 sum(z^2)
    float zacc = 0.f;
    {
        const int v4 = tid & 15;           // 4-vector group
        const int d4 = tid >> 4;           // 4-dim group
        float4 r[4];
#pragma unroll
        for (int i = 0; i < 4; ++i)
            r[i] = *reinterpret_cast<const float4*>(zb + (size_t)(d4 * 4 + i) * 1024 + v4 * 4);
        const float* rf = reinterpret_cast<const float*>(r);
#pragma unroll
        for (int n = 0; n < 16; ++n) zacc = fmaf(rf[n], rf[n], zacc);
#pragma unroll
        for (int j = 0; j < 4; ++j) {
            const int v = v4 * 4 + j;
            uint2 pk;
            pk.x = pk2t(rf[0 * 4 + j], rf[1 * 4 + j]);
            pk.y = pk2t(rf[2 * 4 + j], rf[3 * 4 + j]);
            const int byte = v * 128 + ((d4 * 8) ^ ((v & 7) << 4));
            *reinterpret_cast<uint2*>(zl + byte) = pk;
        }
    }
    __syncthreads();

    const int l16 = lane & 15;
    const int lg  = lane >> 4;    // 0..3

    // ---- B-frags: this block's 64 vectors in registers (32 VGPRs)
    bf16x8 bfr[NG][2];
#pragma unroll
    for (int g = 0; g < NG; ++g)
#pragma unroll
        for (int h = 0; h < 2; ++h) {
            const int v = g * 16 + l16;
            const int byte = v * 128 + (((h * 64) + lg * 16) ^ ((v & 7) << 4));
            bfr[g][h] = *reinterpret_cast<const bf16x8*>(zl + byte);
        }

    // ---- k-loop: software-pipelined (prefetch tile kt+1 regs before compute kt)
    int best[NG];
#pragma unroll
    for (int g = 0; g < NG; ++g) best[g] = 0;

    bf16x8 a0 = *reinterpret_cast<const bf16x8*>(ebf + (size_t)(cw + l16) * 64 + lg * 8);
    bf16x8 a1 = *reinterpret_cast<const bf16x8*>(ebf + (size_t)(cw + l16) * 64 + 32 + lg * 8);
    f32x4  ci = *reinterpret_cast<const f32x4*>(hb + cw + lg * 4);

#pragma unroll 2
    for (int kt = 0; kt < TILES; ++kt) {
        const bf16x8 b0 = a0, b1 = a1;
        const f32x4  cc = ci;
        const int nk = (kt + 1 < TILES) ? kt + 1 : TILES - 1;
        const unsigned short* nrow = ebf + (size_t)(cw + nk * 16 + l16) * 64;
        a0 = *reinterpret_cast<const bf16x8*>(nrow + lg * 8);
        a1 = *reinterpret_cast<const bf16x8*>(nrow + 32 + lg * 8);
        ci = *reinterpret_cast<const f32x4*>(hb + cw + nk * 16 + lg * 4);

        const int idx0 = cw + kt * 16 + lg * 4;
#pragma unroll
        for (int g = 0; g < NG; ++g) {
            f32x4 c = cc;
            c = __builtin_amdgcn_mfma_f32_16x16x32_bf16(b0, bfr[g][0], c, 0, 0, 0);
            c = __builtin_amdgcn_mfma_f32_16x16x32_bf16(b1, bfr[g][1], c, 0, 0, 0);
            const int p0 = (int)((__builtin_bit_cast(unsigned, c[0]) & 0xFFFFFC00u) | (unsigned)(idx0 + 0));
            const int p1 = (int)((__builtin_bit_cast(unsigned, c[1]) & 0xFFFFFC00u) | (unsigned)(idx0 + 1));
            const int p2 = (int)((__builtin_bit_cast(unsigned, c[2]) & 0xFFFFFC00u) | (unsigned)(idx0 + 2));
            const int p3 = (int)((__builtin_bit_cast(unsigned, c[3]) & 0xFFFFFC00u) | (unsigned)(idx0 + 3));
            best[g] = max3i(max3i(p0, p1, p2), p3, best[g]);   // 2x v_max3_i32
        }
    }

    // ---- cross-lane argmax (over lg groups)
#pragma unroll
    for (int g = 0; g < NG; ++g) {
        int tv = best[g];
        int o = __shfl_xor(tv, 16, 64); tv = tv > o ? tv : o;
        o = __shfl_xor(tv, 32, 64);     tv = tv > o ? tv : o;
        if (lane < 16) wv[wave * MB + g * 16 + l16] = tv;
    }
    __syncthreads();

    // ---- cross-wave combine; unpack winning score for the loss
    float tcon = 0.f;
    if (tid < MB) {
        int tv = wv[tid];
#pragma unroll
        for (int w = 1; w < WAVES; ++w) {
            const int o = wv[w * MB + tid];
            tv = tv > o ? tv : o;
        }
        fin[tid] = tv & (K - 1);
        tcon = __builtin_bit_cast(float, (unsigned)tv & 0xFFFFFC00u) - 1.0f;  // z.e - 0.5||e||^2
    }
    __syncthreads();

    // ---- output: gather exact f32 code rows, write out[b][d][hw] coalesced
    {
        const int v  = tid & 63;
        const int dh = tid >> 6;              // 0..3, 16 dims each
        const int idx = fin[v];
        const float4* eq4 = reinterpret_cast<const float4*>(emb + (size_t)idx * D + dh * 16);
        float* ob = out + (size_t)b * (D * 1024) + hw0 + v;
#pragma unroll
        for (int i = 0; i < 4; ++i) {
            const float4 q = eq4[i];
            const int d = dh * 16 + i * 4;
            ob[(size_t)(d + 0) * 1024] = q.x;
            ob[(size_t)(d + 1) * 1024] = q.y;
            ob[(size_t)(d + 2) * 1024] = q.z;
            ob[(size_t)(d + 3) * 1024] = q.w;
        }
    }

    // ---- block partial: sum(z^2) - 2*sum(t), fixed-order tree
    red[tid] = zacc - 2.f * tcon;
    __syncthreads();
#pragma unroll
    for (int s = 128; s > 0; s >>= 1) {
        if (tid < s) red[tid] += red[tid + s];
        __syncthreads();
    }
    if (tid == 0) pP[blk] = red[0];
}

// ---------------------------------------------------------------------------
// Loss epilogue: 1 block; kernel boundary guarantees pP visibility.
// ---------------------------------------------------------------------------
__global__ __launch_bounds__(256) void vq_loss(const float* __restrict__ pP,
                                               float* __restrict__ loss_out) {
    __shared__ float red[256];
    float s = 0.f;
    for (int i = threadIdx.x; i < NBLK; i += 256) s += pP[i];
    red[threadIdx.x] = s;
    __syncthreads();
#pragma unroll
    for (int st = 128; st > 0; st >>= 1) {
        if (threadIdx.x < st) red[threadIdx.x] += red[threadIdx.x + st];
        __syncthreads();
    }
    if (threadIdx.x == 0)
        loss_out[0] = 1.25f * red[0] * (1.0f / (float)((size_t)NVEC * D));
}

extern "C" void kernel_launch(void* const* d_in, const int* in_sizes, int n_in,
                              void* d_out, int out_size, void* d_ws, size_t ws_size,
                              hipStream_t stream) {
    const float* z   = (const float*)d_in[0];   // [64, 64, 32, 32]
    const float* emb = (const float*)d_in[1];   // [1024, 64]
    float* out = (float*)d_out;                 // 4194304 quantized + 1 loss

    char* ws = (char*)d_ws;
    unsigned* ebf_u = (unsigned*)ws;            // 128 KB bf16 codebook
    float* hb = (float*)(ws + 131072);          // 4 KB biased neg half-norms
    float* pP = (float*)(ws + 135168);          // 4 KB block partials

    vq_prep<<<128, 256, 0, stream>>>(emb, ebf_u, hb);
    vq_main<<<NBLK, 256, 0, stream>>>(z, emb, (const unsigned short*)ebf_u, hb, out, pP);
    vq_loss<<<1, 256, 0, stream>>>(pP, out + (size_t)NVEC * D);
}

// Round 11
// 28.298 us; speedup vs baseline: 3.0679x; 1.2426x over previous
//
#include <hip/hip_runtime.h>

#define D 64
#define K 1024
#define NVEC 65536
#define MB 128            // vectors per block
#define NBLK (NVEC / MB)  // 512
#define WAVES 4
#define KPW (K / WAVES)   // 256 codes per wave
#define TILES (KPW / 16)  // 16
#define NG (MB / 16)      // 8 vector groups per wave

typedef __attribute__((ext_vector_type(8))) short bf16x8;
typedef __attribute__((ext_vector_type(4))) float f32x4;

// single v_perm_b32: {hi16(b), hi16(a)} == bf16x2(trunc(a), trunc(b))
__device__ inline unsigned pk2t(float a, float b) {
    return __builtin_amdgcn_perm(__builtin_bit_cast(unsigned, b),
                                 __builtin_bit_cast(unsigned, a), 0x07060302u);
}
__device__ inline int max3i(int a, int b, int c) {   // -> v_max3_i32
    const int m = a > b ? a : b;
    return m > c ? m : c;
}

// ---------------------------------------------------------------------------
// Prep: 128 blocks x 256 thr, 32 threads per codebook row (proven round 10).
// ---------------------------------------------------------------------------
__global__ __launch_bounds__(256) void vq_prep(const float* __restrict__ emb,
                                               unsigned* __restrict__ ebf_u,
                                               float* __restrict__ hb) {
    const int r = blockIdx.x * 8 + (threadIdx.x >> 5);   // 0..1023
    const int j = threadIdx.x & 31;                      // f32-pair within row
    const float2 v = *reinterpret_cast<const float2*>(emb + (size_t)r * D + j * 2);
    ebf_u[(size_t)r * 32 + j] = pk2t(v.x, v.y);
    float s = fmaf(v.x, v.x, v.y * v.y);
#pragma unroll
    for (int off = 1; off < 32; off <<= 1) s += __shfl_xor(s, off, 64);
    if (j == 0) hb[r] = 1.0f - 0.5f * s;
}

// ---------------------------------------------------------------------------
// Main: 256 thr (4 waves), 128 vectors/block, 512 blocks.
// bfr register-resident (launch_bounds(256,2) -> no demotion/spill), depth-2
// register ring prefetch of codebook tiles, packed argmax, loss via unpack.
// ---------------------------------------------------------------------------
__global__ __launch_bounds__(256, 2) void vq_main(const float* __restrict__ z,
                                                  const float* __restrict__ emb,
                                                  const unsigned short* __restrict__ ebf,
                                                  const float* __restrict__ hb,
                                                  float* __restrict__ out,
                                                  float* __restrict__ pP) {
    __shared__ __align__(16) char zl[MB * 128];   // 16 KB bf16 z-tile [v][d], XOR-swizzled
    __shared__ int   wv[WAVES * MB];              // 2 KB
    __shared__ int   fin[MB];
    __shared__ float red[256];

    const int tid = threadIdx.x;
    const int blk = blockIdx.x;
    const int b   = blk >> 3;              // batch (8 blocks per batch)
    const int hw0 = (blk & 7) * MB;        // first spatial pos
    const float* zb = z + (size_t)b * (D * 1024) + hw0;

    const int wave = tid >> 6;
    const int lane = tid & 63;
    const int cw   = wave * KPW;
    const int l16  = lane & 15;
    const int lg   = lane >> 4;    // 0..3

    // ---- stage z tile: f32 [d][v] -> LDS bf16 [v][d] swizzled; f32 sum(z^2)
    float zacc = 0.f;
#pragma unroll
    for (int it = 0; it < 2; ++it) {
        const int item = it * 256 + tid;   // 0..511
        const int v4 = item & 31;          // 4-vector group (128 v)
        const int d4 = item >> 5;          // 4-dim group (64 d)
        float4 r[4];
#pragma unroll
        for (int i = 0; i < 4; ++i)
            r[i] = *reinterpret_cast<const float4*>(zb + (size_t)(d4 * 4 + i) * 1024 + v4 * 4);
        const float* rf = reinterpret_cast<const float*>(r);
#pragma unroll
        for (int n = 0; n < 16; ++n) zacc = fmaf(rf[n], rf[n], zacc);
#pragma unroll
        for (int j = 0; j < 4; ++j) {
            const int v = v4 * 4 + j;
            uint2 pk;
            pk.x = pk2t(rf[0 * 4 + j], rf[1 * 4 + j]);
            pk.y = pk2t(rf[2 * 4 + j], rf[3 * 4 + j]);
            const int byte = v * 128 + ((d4 * 8) ^ ((v & 7) << 4));
            *reinterpret_cast<uint2*>(zl + byte) = pk;
        }
    }

    // ---- depth-2 ring preload of codebook tiles 0,1 (independent of barrier)
    bf16x8 A0[2], A1[2];
    f32x4  CI[2];
#pragma unroll
    for (int p = 0; p < 2; ++p) {
        const unsigned short* row = ebf + (size_t)(cw + p * 16 + l16) * 64;
        A0[p] = *reinterpret_cast<const bf16x8*>(row + lg * 8);
        A1[p] = *reinterpret_cast<const bf16x8*>(row + 32 + lg * 8);
        CI[p] = *reinterpret_cast<const f32x4*>(hb + cw + p * 16 + lg * 4);
    }
    __syncthreads();

    // ---- B-frags: this block's 128 vectors register-resident (64 VGPR)
    bf16x8 bfr[NG][2];
#pragma unroll
    for (int g = 0; g < NG; ++g)
#pragma unroll
        for (int h = 0; h < 2; ++h) {
            const int v = g * 16 + l16;
            const int byte = v * 128 + (((h * 64) + lg * 16) ^ ((v & 7) << 4));
            bfr[g][h] = *reinterpret_cast<const bf16x8*>(zl + byte);
        }

    // ---- k-loop: consume slot, prefetch kt+2 into it, 16 MFMA, packed max3
    int best[NG];
#pragma unroll
    for (int g = 0; g < NG; ++g) best[g] = 0;

#pragma unroll 2
    for (int kt = 0; kt < TILES; ++kt) {
        const int cur = kt & 1;                  // static under unroll 2
        const bf16x8 b0 = A0[cur], b1 = A1[cur];
        const f32x4  cc = CI[cur];
        const int nk = (kt + 2 < TILES) ? kt + 2 : kt;   // tail: harmless reload
        const unsigned short* nrow = ebf + (size_t)(cw + nk * 16 + l16) * 64;
        A0[cur] = *reinterpret_cast<const bf16x8*>(nrow + lg * 8);
        A1[cur] = *reinterpret_cast<const bf16x8*>(nrow + 32 + lg * 8);
        CI[cur] = *reinterpret_cast<const f32x4*>(hb + cw + nk * 16 + lg * 4);

        const int idx0 = cw + kt * 16 + lg * 4;
#pragma unroll
        for (int g = 0; g < NG; ++g) {
            f32x4 c = cc;
            c = __builtin_amdgcn_mfma_f32_16x16x32_bf16(b0, bfr[g][0], c, 0, 0, 0);
            c = __builtin_amdgcn_mfma_f32_16x16x32_bf16(b1, bfr[g][1], c, 0, 0, 0);
            const int p0 = (int)((__builtin_bit_cast(unsigned, c[0]) & 0xFFFFFC00u) | (unsigned)(idx0 + 0));
            const int p1 = (int)((__builtin_bit_cast(unsigned, c[1]) & 0xFFFFFC00u) | (unsigned)(idx0 + 1));
            const int p2 = (int)((__builtin_bit_cast(unsigned, c[2]) & 0xFFFFFC00u) | (unsigned)(idx0 + 2));
            const int p3 = (int)((__builtin_bit_cast(unsigned, c[3]) & 0xFFFFFC00u) | (unsigned)(idx0 + 3));
            best[g] = max3i(max3i(p0, p1, p2), p3, best[g]);   // 2x v_max3_i32
        }
    }

    // ---- cross-lane argmax (over lg groups)
#pragma unroll
    for (int g = 0; g < NG; ++g) {
        int tv = best[g];
        int o = __shfl_xor(tv, 16, 64); tv = tv > o ? tv : o;
        o = __shfl_xor(tv, 32, 64);     tv = tv > o ? tv : o;
        if (lane < 16) wv[wave * MB + g * 16 + l16] = tv;
    }
    __syncthreads();

    // ---- cross-wave combine; unpack winning score for the loss
    float tcon = 0.f;
    if (tid < MB) {
        int tv = wv[tid];
#pragma unroll
        for (int w = 1; w < WAVES; ++w) {
            const int o = wv[w * MB + tid];
            tv = tv > o ? tv : o;
        }
        fin[tid] = tv & (K - 1);
        tcon = __builtin_bit_cast(float, (unsigned)tv & 0xFFFFFC00u) - 1.0f;  // z.e - 0.5||e||^2
    }
    __syncthreads();

    // ---- output: gather exact f32 code rows, write out[b][d][hw] coalesced
    {
        const int v  = tid & 127;
        const int dh = tid >> 7;              // 0..1, 32 dims each
        const int idx = fin[v];
        const float4* eq4 = reinterpret_cast<const float4*>(emb + (size_t)idx * D + dh * 32);
        float* ob = out + (size_t)b * (D * 1024) + hw0 + v;
#pragma unroll
        for (int i = 0; i < 8; ++i) {
            const float4 q = eq4[i];
            const int d = dh * 32 + i * 4;
            ob[(size_t)(d + 0) * 1024] = q.x;
            ob[(size_t)(d + 1) * 1024] = q.y;
            ob[(size_t)(d + 2) * 1024] = q.z;
            ob[(size_t)(d + 3) * 1024] = q.w;
        }
    }

    // ---- block partial: sum(z^2) - 2*sum(t), fixed-order tree
    red[tid] = zacc - 2.f * tcon;
    __syncthreads();
#pragma unroll
    for (int s = 128; s > 0; s >>= 1) {
        if (tid < s) red[tid] += red[tid + s];
        __syncthreads();
    }
    if (tid == 0) pP[blk] = red[0];
}

// ---------------------------------------------------------------------------
// Loss epilogue: 1 block; kernel boundary guarantees pP visibility.
// ---------------------------------------------------------------------------
__global__ __launch_bounds__(256) void vq_loss(const float* __restrict__ pP,
                                               float* __restrict__ loss_out) {
    __shared__ float red[256];
    float s = 0.f;
    for (int i = threadIdx.x; i < NBLK; i += 256) s += pP[i];
    red[threadIdx.x] = s;
    __syncthreads();
#pragma unroll
    for (int st = 128; st > 0; st >>= 1) {
        if (threadIdx.x < st) red[threadIdx.x] += red[threadIdx.x + st];
        __syncthreads();
    }
    if (threadIdx.x == 0)
        loss_out[0] = 1.25f * red[0] * (1.0f / (float)((size_t)NVEC * D));
}

extern "C" void kernel_launch(void* const* d_in, const int* in_sizes, int n_in,
                              void* d_out, int out_size, void* d_ws, size_t ws_size,
                              hipStream_t stream) {
    const float* z   = (const float*)d_in[0];   // [64, 64, 32, 32]
    const float* emb = (const float*)d_in[1];   // [1024, 64]
    float* out = (float*)d_out;                 // 4194304 quantized + 1 loss

    char* ws = (char*)d_ws;
    unsigned* ebf_u = (unsigned*)ws;            // 128 KB bf16 codebook
    float* hb = (float*)(ws + 131072);          // 4 KB biased neg half-norms
    float* pP = (float*)(ws + 135168);          // 2 KB block partials

    vq_prep<<<128, 256, 0, stream>>>(emb, ebf_u, hb);
    vq_main<<<NBLK, 256, 0, stream>>>(z, emb, (const unsigned short*)ebf_u, hb, out, pP);
    vq_loss<<<1, 256, 0, stream>>>(pP, out + (size_t)NVEC * D);
}